// Round 4
// baseline (530.138 us; speedup 1.0000x reference)
//
#include <hip/hip_runtime.h>

#define DMODEL 1024
#define NEXP   32
#define FDIM   512
#define TOPK   4

using short8 = __attribute__((ext_vector_type(8))) short;
using f32x4  = __attribute__((ext_vector_type(4))) float;

__device__ __forceinline__ unsigned short f2b(float f) {
    unsigned int u = __float_as_uint(f);
    unsigned int r = (u + 0x7FFFu + ((u >> 16) & 1u)) >> 16;   // RNE bf16
    return (unsigned short)r;
}

// ---------------- routing: sigmoid gates + top-4 + expert lists ----------------
__global__ __launch_bounds__(256) void route_k(
    const float* __restrict__ x, const float* __restrict__ esel,
    int* __restrict__ counts, int* __restrict__ tok_list,
    float* __restrict__ gate_list, int ntok)
{
    int tok = blockIdx.x;
    __shared__ float xs[DMODEL];
    __shared__ float gs[NEXP];
    const float4* xr = (const float4*)(x + (size_t)tok * DMODEL);
    for (int i = threadIdx.x; i < DMODEL / 4; i += 256)
        ((float4*)xs)[i] = xr[i];
    __syncthreads();

    int e   = threadIdx.x >> 3;
    int sub = threadIdx.x & 7;
    const float* er = esel + (size_t)e * DMODEL;
    float acc = 0.f;
    for (int k = sub * 4; k < DMODEL; k += 32) {
        float4 kv = *(const float4*)(er + k);
        float4 xv = *(const float4*)(xs + k);
        acc += kv.x * xv.x + kv.y * xv.y + kv.z * xv.z + kv.w * xv.w;
    }
    acc += __shfl_xor(acc, 1);
    acc += __shfl_xor(acc, 2);
    acc += __shfl_xor(acc, 4);
    if (sub == 0) gs[e] = 1.f / (1.f + expf(-acc));
    __syncthreads();

    if (threadIdx.x == 0) {
        float g[NEXP];
        for (int i = 0; i < NEXP; i++) g[i] = gs[i];
        for (int k = 0; k < TOPK; k++) {
            int bi = 0; float bv = g[0];
            for (int i = 1; i < NEXP; i++) if (g[i] > bv) { bv = g[i]; bi = i; }
            g[bi] = -1e30f;
            int pos = atomicAdd(&counts[bi], 1);
            tok_list [(size_t)bi * ntok + pos] = tok;
            gate_list[(size_t)bi * ntok + pos] = bv;
        }
    }
}

// ---------------- prep: x fp32 -> bf16 ----------------
__global__ __launch_bounds__(256) void prep_x(const float* __restrict__ x,
                                              unsigned short* __restrict__ xb, int n4) {
    int i = blockIdx.x * 256 + threadIdx.x;
    if (i >= n4) return;
    float4 v = ((const float4*)x)[i];
    ushort4 o;
    o.x = f2b(v.x); o.y = f2b(v.y); o.z = f2b(v.z); o.w = f2b(v.w);
    ((ushort4*)xb)[i] = o;
}

// ------- prep: transpose+convert  src[e][R][C] f32  ->  dst[e][C][R] bf16 -------
__global__ __launch_bounds__(256) void prep_t(const float* __restrict__ src,
                                              unsigned short* __restrict__ dst,
                                              int R, int C) {
    __shared__ float tile[64][65];
    int e  = blockIdx.z;
    int r0 = blockIdx.y * 64, c0 = blockIdx.x * 64;
    const float* s = src + (size_t)e * R * C;
    unsigned short* d = dst + (size_t)e * R * C;
    for (int i = 0; i < 16; i++) {
        int c = i * 256 + threadIdx.x;
        int rr = c >> 6, cc = c & 63;
        tile[rr][cc] = s[(size_t)(r0 + rr) * C + c0 + cc];
    }
    __syncthreads();
    for (int i = 0; i < 16; i++) {
        int c = i * 256 + threadIdx.x;
        int wr = c >> 6, wc = c & 63;     // dst element (row c0+wr, col r0+wc)
        d[(size_t)(c0 + wr) * R + r0 + wc] = f2b(tile[wc][wr]);
    }
}

// ---------------- MFMA expert kernel: BT=64 tokens, 4 waves split N ----------------
#define BTM 64
#define XP  40    // Xp pitch (bf16 elems): 80B, 80/16=5 odd -> uniform bank-quads
#define WPP 40
#define HP  520   // hs pitch: 1040B, 1040/16=65 odd

__global__ __launch_bounds__(256) void expert_mfma(
    const unsigned short* __restrict__ xb,
    const unsigned short* __restrict__ kt,   // [E][512][1024] bf16 (f-major)
    const unsigned short* __restrict__ vt,   // [E][1024][512] bf16 (v-major)
    const int* __restrict__ counts,
    const int* __restrict__ tok_list, const float* __restrict__ gate_list,
    float* __restrict__ out, int ntok)
{
    int e   = blockIdx.y;
    int cnt = counts[e];
    int t0  = blockIdx.x * BTM;
    if (t0 >= cnt) return;
    int live = min(BTM, cnt - t0);

    __shared__ unsigned short Xp[BTM * XP];       // 5 KB
    __shared__ unsigned short Wp[512 * WPP];      // 40 KB
    __shared__ unsigned short hsb[BTM * HP];      // 65 KB
    __shared__ int   toks[BTM];
    __shared__ float gts[BTM];

    int tid  = threadIdx.x;
    int lane = tid & 63;
    int w    = tid >> 6;        // wave 0..3
    int lr   = lane & 15;
    int lg   = lane >> 4;       // k-group 0..3

    if (tid < BTM) {
        bool lv = tid < live;
        toks[tid] = lv ? tok_list [(size_t)e * ntok + t0 + tid] : 0;
        gts[tid]  = lv ? gate_list[(size_t)e * ntok + t0 + tid] : 0.f;
    }
    __syncthreads();

    // ================= stage 1: h[t][f] = relu(sum_d x[t][d] * keys[d][f]) * gate =================
    f32x4 acc[4][8];
    #pragma unroll
    for (int m = 0; m < 4; m++)
        #pragma unroll
        for (int n = 0; n < 8; n++)
            acc[m][n] = (f32x4){0.f, 0.f, 0.f, 0.f};

    const unsigned short* ke = kt + (size_t)e * FDIM * DMODEL;
    for (int k0 = 0; k0 < DMODEL; k0 += 32) {
        {   // stage Xp: 64 rows x 32 k (256 x 16B chunks)
            int r = tid >> 2, q = tid & 3;
            short8 v = *(const short8*)(xb + (size_t)toks[r] * DMODEL + k0 + q * 8);
            *(short8*)(Xp + r * XP + q * 8) = v;
        }
        #pragma unroll
        for (int i = 0; i < 8; i++) {   // stage Wp: 512 rows x 32 k
            int c = i * 256 + tid;
            int r = c >> 2, q = c & 3;
            short8 v = *(const short8*)(ke + (size_t)r * DMODEL + k0 + q * 8);
            *(short8*)(Wp + r * WPP + q * 8) = v;
        }
        __syncthreads();
        short8 a[4];
        #pragma unroll
        for (int m = 0; m < 4; m++)
            a[m] = *(const short8*)(Xp + (m * 16 + lr) * XP + lg * 8);
        #pragma unroll
        for (int n = 0; n < 8; n++) {
            short8 b = *(const short8*)(Wp + (w * 128 + n * 16 + lr) * WPP + lg * 8);
            #pragma unroll
            for (int m = 0; m < 4; m++)
                acc[m][n] = __builtin_amdgcn_mfma_f32_16x16x32_bf16(a[m], b, acc[m][n], 0, 0, 0);
        }
        __syncthreads();
    }
    // hs writeback: D row = lg*4+r (token-within-tile), col = lane&15 (f)
    #pragma unroll
    for (int m = 0; m < 4; m++) {
        #pragma unroll
        for (int n = 0; n < 8; n++) {
            int col = w * 128 + n * 16 + lr;
            #pragma unroll
            for (int r = 0; r < 4; r++) {
                int row = m * 16 + lg * 4 + r;
                float v = fmaxf(acc[m][n][r], 0.f) * gts[row];
                hsb[row * HP + col] = f2b(v);
            }
        }
    }
    __syncthreads();

    // ================= stage 2: out[t][v] += sum_f h[t][f] * values[f][v] =================
    const unsigned short* ve = vt + (size_t)e * DMODEL * FDIM;
    for (int half = 0; half < 2; half++) {
        f32x4 acc2[4][8];
        #pragma unroll
        for (int m = 0; m < 4; m++)
            #pragma unroll
            for (int n = 0; n < 8; n++)
                acc2[m][n] = (f32x4){0.f, 0.f, 0.f, 0.f};

        for (int k0 = 0; k0 < FDIM; k0 += 32) {
            #pragma unroll
            for (int i = 0; i < 8; i++) {   // stage Wp: 512 v-rows x 32 f
                int c = i * 256 + tid;
                int r = c >> 2, q = c & 3;
                short8 v = *(const short8*)(ve + (size_t)(half * 512 + r) * FDIM + k0 + q * 8);
                *(short8*)(Wp + r * WPP + q * 8) = v;
            }
            __syncthreads();
            short8 a[4];
            #pragma unroll
            for (int m = 0; m < 4; m++)
                a[m] = *(const short8*)(hsb + (m * 16 + lr) * HP + k0 + lg * 8);
            #pragma unroll
            for (int n = 0; n < 8; n++) {
                short8 b = *(const short8*)(Wp + (w * 128 + n * 16 + lr) * WPP + lg * 8);
                #pragma unroll
                for (int m = 0; m < 4; m++)
                    acc2[m][n] = __builtin_amdgcn_mfma_f32_16x16x32_bf16(a[m], b, acc2[m][n], 0, 0, 0);
            }
            __syncthreads();
        }
        #pragma unroll
        for (int m = 0; m < 4; m++) {
            #pragma unroll
            for (int r = 0; r < 4; r++) {
                int row = m * 16 + lg * 4 + r;
                if (row < live) {
                    float* orow = out + (size_t)toks[row] * DMODEL + half * 512 + w * 128;
                    #pragma unroll
                    for (int n = 0; n < 8; n++)
                        atomicAdd(orow + n * 16 + lr, acc2[m][n][r]);
                }
            }
        }
    }
}

// ---------------- fp32 fallback expert kernel (used if ws too small) ----------------
#define BTF 16
__global__ __launch_bounds__(256) void expert_k(
    const float* __restrict__ x, const float* __restrict__ keys,
    const float* __restrict__ values, const int* __restrict__ counts,
    const int* __restrict__ tok_list, const float* __restrict__ gate_list,
    float* __restrict__ out, int ntok)
{
    int e   = blockIdx.y;
    int cnt = counts[e];
    int t0  = blockIdx.x * BTF;
    if (t0 >= cnt) return;
    int nt = (cnt - t0 < BTF) ? (cnt - t0) : BTF;

    __shared__ float xs[BTF][DMODEL];
    __shared__ float hs[BTF][FDIM];
    __shared__ int   toks[BTF];
    __shared__ float gts[BTF];

    if (threadIdx.x < BTF) {
        int t = threadIdx.x;
        bool live = (t < nt);
        toks[t] = live ? tok_list [(size_t)e * ntok + t0 + t] : 0;
        gts[t]  = live ? gate_list[(size_t)e * ntok + t0 + t] : 0.f;
    }
    __syncthreads();
    for (int i = threadIdx.x; i < BTF * (DMODEL / 4); i += 256) {
        int r = i >> 8, c = i & 255;
        ((float4*)xs[r])[c] = ((const float4*)(x + (size_t)toks[r] * DMODEL))[c];
    }
    __syncthreads();

    {
        int f = threadIdx.x * 2;
        float acc0[BTF], acc1[BTF];
        #pragma unroll
        for (int t = 0; t < BTF; t++) { acc0[t] = 0.f; acc1[t] = 0.f; }
        const float* kp = keys + (size_t)e * DMODEL * FDIM + f;
        for (int k = 0; k < DMODEL; k += 4) {
            const float* kr = kp + (size_t)k * FDIM;
            float2 kv0 = *(const float2*)(kr);
            float2 kv1 = *(const float2*)(kr + FDIM);
            float2 kv2 = *(const float2*)(kr + 2 * FDIM);
            float2 kv3 = *(const float2*)(kr + 3 * FDIM);
            #pragma unroll
            for (int t = 0; t < BTF; t++) {
                float4 xv = *(const float4*)(&xs[t][k]);
                acc0[t] += xv.x * kv0.x + xv.y * kv1.x + xv.z * kv2.x + xv.w * kv3.x;
                acc1[t] += xv.x * kv0.y + xv.y * kv1.y + xv.z * kv2.y + xv.w * kv3.y;
            }
        }
        #pragma unroll
        for (int t = 0; t < BTF; t++) {
            float g = gts[t];
            hs[t][f]     = fmaxf(acc0[t], 0.f) * g;
            hs[t][f + 1] = fmaxf(acc1[t], 0.f) * g;
        }
    }
    __syncthreads();

    {
        int v = threadIdx.x * 4;
        float acc[BTF][4];
        #pragma unroll
        for (int t = 0; t < BTF; t++) { acc[t][0]=0.f; acc[t][1]=0.f; acc[t][2]=0.f; acc[t][3]=0.f; }
        const float* vp = values + (size_t)e * FDIM * DMODEL + v;
        for (int k = 0; k < FDIM; k += 2) {
            float4 va0 = *(const float4*)(vp + (size_t)k * DMODEL);
            float4 va1 = *(const float4*)(vp + (size_t)(k + 1) * DMODEL);
            #pragma unroll
            for (int t = 0; t < BTF; t++) {
                float2 hv = *(const float2*)(&hs[t][k]);
                acc[t][0] += hv.x * va0.x + hv.y * va1.x;
                acc[t][1] += hv.x * va0.y + hv.y * va1.y;
                acc[t][2] += hv.x * va0.z + hv.y * va1.z;
                acc[t][3] += hv.x * va0.w + hv.y * va1.w;
            }
        }
        #pragma unroll
        for (int t = 0; t < BTF; t++) {
            if (t < nt) {
                float* orow = out + (size_t)toks[t] * DMODEL + v;
                atomicAdd(orow + 0, acc[t][0]);
                atomicAdd(orow + 1, acc[t][1]);
                atomicAdd(orow + 2, acc[t][2]);
                atomicAdd(orow + 3, acc[t][3]);
            }
        }
    }
}

extern "C" void kernel_launch(void* const* d_in, const int* in_sizes, int n_in,
                              void* d_out, int out_size, void* d_ws, size_t ws_size,
                              hipStream_t stream) {
    const float* x      = (const float*)d_in[0];
    const float* esel   = (const float*)d_in[1];
    const float* keys   = (const float*)d_in[2];
    const float* values = (const float*)d_in[3];
    float* out = (float*)d_out;
    int ntok = in_sizes[0] / DMODEL;

    // workspace layout
    const size_t OFF_TOK  = 1024;
    const size_t OFF_GATE = OFF_TOK + (size_t)NEXP * ntok * sizeof(int);
    const size_t OFF_XB   = 2ull << 20;
    const size_t OFF_KT   = 12ull << 20;
    const size_t OFF_VT   = 44ull << 20;
    const size_t NEED     = 76ull << 20;

    int*   counts    = (int*)d_ws;
    int*   tok_list  = (int*)((char*)d_ws + OFF_TOK);
    float* gate_list = (float*)((char*)d_ws + OFF_GATE);

    hipMemsetAsync(counts, 0, NEXP * sizeof(int), stream);
    hipMemsetAsync(out, 0, (size_t)out_size * sizeof(float), stream);

    route_k<<<ntok, 256, 0, stream>>>(x, esel, counts, tok_list, gate_list, ntok);

    if (ws_size >= NEED) {
        unsigned short* xb = (unsigned short*)((char*)d_ws + OFF_XB);
        unsigned short* kt = (unsigned short*)((char*)d_ws + OFF_KT);
        unsigned short* vt = (unsigned short*)((char*)d_ws + OFF_VT);

        int n4 = ntok * DMODEL / 4;
        prep_x<<<(n4 + 255) / 256, 256, 0, stream>>>(x, xb, n4);
        prep_t<<<dim3(FDIM / 64, DMODEL / 64, NEXP), 256, 0, stream>>>(keys,   kt, DMODEL, FDIM);
        prep_t<<<dim3(DMODEL / 64, FDIM / 64, NEXP), 256, 0, stream>>>(values, vt, FDIM, DMODEL);

        int ntiles = (ntok + BTM - 1) / BTM;
        expert_mfma<<<dim3(ntiles, NEXP), 256, 0, stream>>>(
            xb, kt, vt, counts, tok_list, gate_list, out, ntok);
    } else {
        int ntiles = (ntok + BTF - 1) / BTF;
        expert_k<<<dim3(ntiles, NEXP), 256, 0, stream>>>(
            x, keys, values, counts, tok_list, gate_list, out, ntok);
    }
}